// Round 9
// baseline (169.525 us; speedup 1.0000x reference)
//
#include <hip/hip_runtime.h>
#include <hip/hip_bf16.h>
#include <math.h>

#define N_NODES 50000
#define N_EDGES 800000
#define NSLICE 8
#define SLICE_SZ 100000  // N_EDGES / NSLICE

typedef unsigned int uint;
typedef unsigned short ushort;
typedef __attribute__((ext_vector_type(8))) short bf16x8;
typedef __attribute__((ext_vector_type(4))) float f32x4;

__device__ __forceinline__ float bf16_lo(uint u) { return __uint_as_float(u << 16); }
__device__ __forceinline__ float bf16_hi(uint u) { return __uint_as_float(u & 0xFFFF0000u); }
__device__ __forceinline__ ushort f2bf(float a) {
    return __bfloat16_as_ushort(__float2bfloat16(a));
}
__device__ __forceinline__ uint pack_bf2(float a, float b) {
    return ((uint)f2bf(b) << 16) | (uint)f2bf(a);
}

// ---------------- setup: zero counts/total, transpose+convert W1/W2, zero pad rows
__global__ __launch_bounds__(256) void setup_kernel(const float* __restrict__ W1,
                                                    const float* __restrict__ W2,
                                                    int* __restrict__ counts,
                                                    ushort* __restrict__ W1t,
                                                    ushort* __restrict__ W2t,
                                                    ushort* __restrict__ h1pad,
                                                    ushort* __restrict__ h2pad) {
    int i = blockIdx.x * 256 + threadIdx.x;
    if (i < N_NODES + 64) {  // counts | total
        counts[i] = 0;
        return;
    }
    i -= N_NODES + 64;
    if (i < 128 * 128) {  // W1t[n][k] = bf16(W1[k][n]), coalesced read
        int k = i >> 7, n = i & 127;
        W1t[n * 128 + k] = f2bf(W1[i]);
        return;
    }
    i -= 128 * 128;
    if (i < 128 * 64) {
        int k = i >> 6, n = i & 63;
        W2t[n * 128 + k] = f2bf(W2[i]);
        return;
    }
    i -= 128 * 64;
    if (i < 128) {  // ZERO_NODE pad rows
        h1pad[i] = 0;
        return;
    }
    i -= 128;
    if (i < 64) h2pad[i] = 0;
}

// counts[dst] += 1 per edge; atomic return value = this edge's rank within dst
__global__ void count_kernel(const int* __restrict__ ei, int* __restrict__ counts,
                             int* __restrict__ rank) {
    int i = blockIdx.x * blockDim.x + threadIdx.x;
    if (i < N_EDGES) {
        int dst = ei[N_EDGES + i];
        rank[i] = atomicAdd(&counts[dst], 1);
    }
}

// Allocate disjoint CSR ranges: off[i] = global cursor bump by counts[i].
__global__ __launch_bounds__(256) void alloc_kernel(const int* __restrict__ counts,
                                                    int* __restrict__ off,
                                                    float* __restrict__ dinv,
                                                    int* __restrict__ total) {
    __shared__ int wsum[4];
    __shared__ int wbase[4];
    int t = threadIdx.x;
    int lane = t & 63;
    int w = t >> 6;
    int i = blockIdx.x * 256 + t;
    int c = (i < N_NODES) ? counts[i] : 0;

    int incl = c;
#pragma unroll
    for (int o = 1; o < 64; o <<= 1) {
        int v = __shfl_up(incl, o, 64);
        if (lane >= o) incl += v;
    }
    if (lane == 63) wsum[w] = incl;
    __syncthreads();
    if (t == 0) {
        int s0 = wsum[0], s1 = wsum[1], s2 = wsum[2], s3 = wsum[3];
        int base = atomicAdd(total, s0 + s1 + s2 + s3);
        wbase[0] = base;
        wbase[1] = base + s0;
        wbase[2] = base + s0 + s1;
        wbase[3] = base + s0 + s1 + s2;
    }
    __syncthreads();
    if (i < N_NODES) {
        off[i] = wbase[w] + incl - c;
        dinv[i] = rsqrtf((float)(c + 1));
    }
}

// psrc[i] = {csr slot, src} per edge (coalesced; one int2 stream for fill)
__global__ void pos_kernel(const int* __restrict__ ei, const int* __restrict__ off,
                           const int* __restrict__ rank, int2* __restrict__ psrc) {
    int i = blockIdx.x * blockDim.x + threadIdx.x;
    if (i < N_EDGES) {
        psrc[i] = make_int2(off[ei[N_EDGES + i]] + rank[i], ei[i]);
    }
}

// XCD-sliced scatter (each 1/8 csr range written by one XCD's blocks -> lines
// merge in that XCD's L2 instead of bouncing via HBM)
__global__ __launch_bounds__(256) void fill_kernel(const int2* __restrict__ psrc,
                                                   int* __restrict__ csr) {
    int slice = blockIdx.x & (NSLICE - 1);
    int chunk = blockIdx.x / NSLICE;
    int lo = slice * SLICE_SZ;
    int hi = lo + SLICE_SZ;
    int base = chunk * 1024 + threadIdx.x * 4;
    if (base + 3 < N_EDGES) {
        int4 a = reinterpret_cast<const int4*>(psrc + base)[0];  // {p0,s0,p1,s1}
        int4 b = reinterpret_cast<const int4*>(psrc + base)[1];  // {p2,s2,p3,s3}
        if (a.x >= lo && a.x < hi) csr[a.x] = a.y;
        if (a.z >= lo && a.z < hi) csr[a.z] = a.w;
        if (b.x >= lo && b.x < hi) csr[b.x] = b.y;
        if (b.z >= lo && b.z < hi) csr[b.z] = b.w;
    } else {
        for (int e = base; e < N_EDGES && e < base + 4; e++) {
            int2 ps = psrc[e];
            if (ps.x >= lo && ps.x < hi) csr[ps.x] = ps.y;
        }
    }
}

// ---------------- MFMA GEMM: H[N,C_OUT] = bf16( dinv[n] * (A @ Wt^T) )
// A is f32 (layer 1: X) or bf16 (layer 2: g1); f32 is packed to bf16 in-register.
template <int C_OUT, bool A_F32>
__global__ __launch_bounds__(256) void gemm_mfma(const void* __restrict__ Ain,
                                                 const ushort* __restrict__ Wt,
                                                 const float* __restrict__ dinv,
                                                 ushort* __restrict__ H) {
    int lane = threadIdx.x & 63;
    int w = threadIdx.x >> 6;
    int m = lane & 15;
    int q = lane >> 4;
    int rowTile, nbase;
    if constexpr (C_OUT == 128) {
        rowTile = blockIdx.x * 2 + (w >> 1);
        nbase = (w & 1) * 64;
    } else {
        rowTile = blockIdx.x * 4 + w;
        nbase = 0;
    }
    if (rowTile >= N_NODES / 16) return;  // 50000 = 16*3125, exact

    bf16x8 afrag[4];
    if constexpr (A_F32) {
        const float* arow = (const float*)Ain + (size_t)(rowTile * 16 + m) * 128 + q * 8;
#pragma unroll
        for (int kt = 0; kt < 4; kt++) {
            float4 lo = *reinterpret_cast<const float4*>(arow + kt * 32);
            float4 hi = *reinterpret_cast<const float4*>(arow + kt * 32 + 4);
            uint4 u;
            u.x = pack_bf2(lo.x, lo.y);
            u.y = pack_bf2(lo.z, lo.w);
            u.z = pack_bf2(hi.x, hi.y);
            u.w = pack_bf2(hi.z, hi.w);
            afrag[kt] = *reinterpret_cast<bf16x8*>(&u);
        }
    } else {
        const ushort* arow = (const ushort*)Ain + (size_t)(rowTile * 16 + m) * 128 + q * 8;
#pragma unroll
        for (int kt = 0; kt < 4; kt++)
            afrag[kt] = *reinterpret_cast<const bf16x8*>(arow + kt * 32);
    }

    const ushort* brow = Wt + (size_t)(nbase + m) * 128 + q * 8;
    f32x4 acc[4];
#pragma unroll
    for (int nt = 0; nt < 4; nt++) {
        acc[nt] = {0.f, 0.f, 0.f, 0.f};
        const ushort* bp = brow + (size_t)nt * 16 * 128;
#pragma unroll
        for (int kt = 0; kt < 4; kt++) {
            bf16x8 bfrag = *reinterpret_cast<const bf16x8*>(bp + kt * 32);
            acc[nt] = __builtin_amdgcn_mfma_f32_16x16x32_bf16(afrag[kt], bfrag, acc[nt], 0, 0, 0);
        }
    }

    int rbase = rowTile * 16 + q * 4;
#pragma unroll
    for (int r = 0; r < 4; r++) {
        float dn = dinv[rbase + r];
#pragma unroll
        for (int nt = 0; nt < 4; nt++) {
            H[(size_t)(rbase + r) * C_OUT + nbase + nt * 16 + m] =
                f2bf(acc[nt][r] * dn);
        }
    }
}

// ---------------- aggregation: OUT[n] = dinv[n]*(H[n] + sum_e H[s]) + b
// H pre-scaled by dinv, bf16, with a zeroed pad row at index N_NODES so
// out-of-range edge slots gather exact zeros -> no masking in the inner loop.
// C=128: quarter-wave (16 lanes x uint4 = 256B row), 4 edges/gather-inst.
// C=64 : 8-lane groups (8 lanes x uint4 = 128B row), 8 edges/gather-inst.
template <int C, bool RELU, bool OUT_BF16>
__global__ __launch_bounds__(256) void agg_kernel(const __hip_bfloat16* __restrict__ Hb,
                                                  const int* __restrict__ off,
                                                  const int* __restrict__ counts,
                                                  const int* __restrict__ csr_src,
                                                  const float* __restrict__ dinv,
                                                  const float* __restrict__ bias,
                                                  void* __restrict__ OUT) {
    int wave = threadIdx.x >> 6;
    int lane = threadIdx.x & 63;
    int n = blockIdx.x * 4 + wave;
    if (n >= N_NODES) return;

    float dn = dinv[n];
    int e0 = off[n];
    int cnt = counts[n];

    if constexpr (C == 128) {
        int ql = lane & 15;
        int quarter = lane >> 4;
        float a[8];
        {
            uint4 u = reinterpret_cast<const uint4*>(Hb + (size_t)n * C)[ql];
            a[0] = quarter ? 0.f : bf16_lo(u.x);
            a[1] = quarter ? 0.f : bf16_hi(u.x);
            a[2] = quarter ? 0.f : bf16_lo(u.y);
            a[3] = quarter ? 0.f : bf16_hi(u.y);
            a[4] = quarter ? 0.f : bf16_lo(u.z);
            a[5] = quarter ? 0.f : bf16_hi(u.z);
            a[6] = quarter ? 0.f : bf16_lo(u.w);
            a[7] = quarter ? 0.f : bf16_hi(u.w);
        }
        for (int c = 0; c < cnt; c += 64) {
            int m = cnt - c;
            if (m > 64) m = 64;
            int my = (lane < m) ? csr_src[e0 + c + lane] : N_NODES;  // pad row = zeros
            for (int j = 0; j < m; j += 32) {
                int s[8];
                uint4 v[8];
#pragma unroll
                for (int k = 0; k < 8; k++) s[k] = __shfl(my, j + 4 * k + quarter, 64);
#pragma unroll
                for (int k = 0; k < 8; k++)
                    v[k] = reinterpret_cast<const uint4*>(Hb + (size_t)s[k] * C)[ql];
#pragma unroll
                for (int k = 0; k < 8; k++) {
                    a[0] += bf16_lo(v[k].x);
                    a[1] += bf16_hi(v[k].x);
                    a[2] += bf16_lo(v[k].y);
                    a[3] += bf16_hi(v[k].y);
                    a[4] += bf16_lo(v[k].z);
                    a[5] += bf16_hi(v[k].z);
                    a[6] += bf16_lo(v[k].w);
                    a[7] += bf16_hi(v[k].w);
                }
            }
        }
#pragma unroll
        for (int r = 0; r < 8; r++) {
            a[r] += __shfl_xor(a[r], 16, 64);
            a[r] += __shfl_xor(a[r], 32, 64);
        }
        if (quarter == 0) {
            float o[8];
#pragma unroll
            for (int r = 0; r < 8; r++) {
                o[r] = fmaf(a[r], dn, bias[8 * ql + r]);
                if (RELU) o[r] = fmaxf(o[r], 0.f);
            }
            if constexpr (OUT_BF16) {
                uint4 u;
                u.x = pack_bf2(o[0], o[1]);
                u.y = pack_bf2(o[2], o[3]);
                u.z = pack_bf2(o[4], o[5]);
                u.w = pack_bf2(o[6], o[7]);
                reinterpret_cast<uint4*>(OUT)[(size_t)n * 16 + ql] = u;
            } else {
                reinterpret_cast<float4*>(OUT)[(size_t)n * 32 + 2 * ql] =
                    make_float4(o[0], o[1], o[2], o[3]);
                reinterpret_cast<float4*>(OUT)[(size_t)n * 32 + 2 * ql + 1] =
                    make_float4(o[4], o[5], o[6], o[7]);
            }
        }
    } else {
        // C == 64: 8 groups of 8 lanes; lane gl covers channels 8*gl..8*gl+7
        int gl = lane & 7;
        int group = lane >> 3;
        float a[8];
        {
            uint4 u = reinterpret_cast<const uint4*>(Hb + (size_t)n * C)[gl];
            a[0] = group ? 0.f : bf16_lo(u.x);
            a[1] = group ? 0.f : bf16_hi(u.x);
            a[2] = group ? 0.f : bf16_lo(u.y);
            a[3] = group ? 0.f : bf16_hi(u.y);
            a[4] = group ? 0.f : bf16_lo(u.z);
            a[5] = group ? 0.f : bf16_hi(u.z);
            a[6] = group ? 0.f : bf16_lo(u.w);
            a[7] = group ? 0.f : bf16_hi(u.w);
        }
        for (int c = 0; c < cnt; c += 64) {
            int m = cnt - c;
            if (m > 64) m = 64;
            int my = (lane < m) ? csr_src[e0 + c + lane] : N_NODES;  // pad row = zeros
            int s[8];
            uint4 v[8];
#pragma unroll
            for (int k = 0; k < 8; k++) s[k] = __shfl(my, 8 * k + group, 64);
#pragma unroll
            for (int k = 0; k < 8; k++)
                v[k] = reinterpret_cast<const uint4*>(Hb + (size_t)s[k] * C)[gl];
#pragma unroll
            for (int k = 0; k < 8; k++) {
                a[0] += bf16_lo(v[k].x);
                a[1] += bf16_hi(v[k].x);
                a[2] += bf16_lo(v[k].y);
                a[3] += bf16_hi(v[k].y);
                a[4] += bf16_lo(v[k].z);
                a[5] += bf16_hi(v[k].z);
                a[6] += bf16_lo(v[k].w);
                a[7] += bf16_hi(v[k].w);
            }
        }
#pragma unroll
        for (int r = 0; r < 8; r++) {
            a[r] += __shfl_xor(a[r], 8, 64);
            a[r] += __shfl_xor(a[r], 16, 64);
            a[r] += __shfl_xor(a[r], 32, 64);
        }
        if (group == 0) {
            float o[8];
#pragma unroll
            for (int r = 0; r < 8; r++) {
                o[r] = fmaf(a[r], dn, bias[8 * gl + r]);
                if (RELU) o[r] = fmaxf(o[r], 0.f);
            }
            if constexpr (OUT_BF16) {
                uint4 u;
                u.x = pack_bf2(o[0], o[1]);
                u.y = pack_bf2(o[2], o[3]);
                u.z = pack_bf2(o[4], o[5]);
                u.w = pack_bf2(o[6], o[7]);
                reinterpret_cast<uint4*>(OUT)[(size_t)n * 8 + gl] = u;
            } else {
                reinterpret_cast<float4*>(OUT)[(size_t)n * 16 + 2 * gl] =
                    make_float4(o[0], o[1], o[2], o[3]);
                reinterpret_cast<float4*>(OUT)[(size_t)n * 16 + 2 * gl + 1] =
                    make_float4(o[4], o[5], o[6], o[7]);
            }
        }
    }
}

// ---------------- launch ----------------
extern "C" void kernel_launch(void* const* d_in, const int* in_sizes, int n_in,
                              void* d_out, int out_size, void* d_ws, size_t ws_size,
                              hipStream_t stream) {
    const float* x  = (const float*)d_in[0];
    const int*   ei = (const int*)d_in[1];
    const float* W1 = (const float*)d_in[2];
    const float* b1 = (const float*)d_in[3];
    const float* W2 = (const float*)d_in[4];
    const float* b2 = (const float*)d_in[5];
    float* out = (float*)d_out;

    char* ws = (char*)d_ws;
    auto alloc = [&](size_t bytes) -> char* {
        char* p = ws;
        ws += (bytes + 255) / 256 * 256;
        return p;
    };
    int* counts = (int*)alloc((size_t)(N_NODES + 64) * 4);  // counts | total
    int* total = counts + N_NODES;
    int* off = (int*)alloc((size_t)(N_NODES + 1) * 4);
    int* rank = (int*)alloc((size_t)N_EDGES * 4);
    int2* psrc = (int2*)alloc((size_t)N_EDGES * 8);
    int* csr = (int*)alloc((size_t)N_EDGES * 4);
    float* dinv = (float*)alloc((size_t)N_NODES * 4);
    ushort* W1t = (ushort*)alloc((size_t)128 * 128 * 2);
    ushort* W2t = (ushort*)alloc((size_t)64 * 128 * 2);
    ushort* h1 = (ushort*)alloc((size_t)(N_NODES + 1) * 128 * 2);  // +ZERO_NODE pad row
    ushort* g1 = (ushort*)alloc((size_t)N_NODES * 128 * 2);        // relu'd layer-1, bf16
    ushort* h2 = (ushort*)alloc((size_t)(N_NODES + 1) * 64 * 2);   // +ZERO_NODE pad row

    const int SETUP_N = (N_NODES + 64) + 128 * 128 + 128 * 64 + 128 + 64;
    setup_kernel<<<(SETUP_N + 255) / 256, 256, 0, stream>>>(
        W1, W2, counts, W1t, W2t, h1 + (size_t)N_NODES * 128, h2 + (size_t)N_NODES * 64);
    count_kernel<<<(N_EDGES + 255) / 256, 256, 0, stream>>>(ei, counts, rank);
    alloc_kernel<<<(N_NODES + 255) / 256, 256, 0, stream>>>(counts, off, dinv, total);
    pos_kernel<<<(N_EDGES + 255) / 256, 256, 0, stream>>>(ei, off, rank, psrc);
    fill_kernel<<<((N_EDGES + 1023) / 1024) * NSLICE, 256, 0, stream>>>(psrc, csr);

    gemm_mfma<128, true><<<(N_NODES / 16 + 1) / 2, 256, 0, stream>>>(x, W1t, dinv, h1);
    agg_kernel<128, true, true><<<(N_NODES + 3) / 4, 256, 0, stream>>>(
        (const __hip_bfloat16*)h1, off, counts, csr, dinv, b1, g1);
    gemm_mfma<64, false><<<(N_NODES / 16 + 3) / 4, 256, 0, stream>>>(g1, W2t, dinv, h2);
    agg_kernel<64, false, false><<<(N_NODES + 3) / 4, 256, 0, stream>>>(
        (const __hip_bfloat16*)h2, off, counts, csr, dinv, b2, out);
}